// Round 1
// baseline (907.140 us; speedup 1.0000x reference)
//
#include <hip/hip_runtime.h>
#include <hip/hip_bf16.h>
#include <math.h>

#define N_DIM 1024
#define L_SEQ 16384

// ---------------- elementwise helpers ----------------

__global__ __launch_bounds__(256) void k_scaleE(float* __restrict__ E,
    const float* __restrict__ A, const float* __restrict__ ls) {
  int i = blockIdx.x * 256 + threadIdx.x;
  float h = 0.5f * expf(ls[0]);
  E[i] = h * A[i];
}

__global__ __launch_bounds__(256) void k_add(float* __restrict__ out,
    const float* __restrict__ a, const float* __restrict__ b) {
  int i = blockIdx.x * 256 + threadIdx.x;
  out[i] = a[i] + b[i];
}

// Ab = 2*S + I
__global__ __launch_bounds__(256) void k_mkAb(float* __restrict__ out,
    const float* __restrict__ S) {
  int i = blockIdx.x * 256 + threadIdx.x;
  int row = i >> 10, col = i & (N_DIM - 1);
  out[i] = 2.0f * S[i] + ((row == col) ? 1.0f : 0.0f);
}

// Bb = step*(B + S@B), written into V column 0 (ld = 128)
__global__ __launch_bounds__(256) void k_bb(float* __restrict__ V,
    const float* __restrict__ S, const float* __restrict__ B,
    const float* __restrict__ ls) {
  int row = blockIdx.x * 4 + (threadIdx.x >> 6);
  int lane = threadIdx.x & 63;
  const float* Sr = S + (size_t)row * N_DIM;
  float sum = 0.f;
  for (int k = lane; k < N_DIM; k += 64) sum += Sr[k] * B[k];
  for (int off = 32; off; off >>= 1) sum += __shfl_down(sum, off);
  if (lane == 0) {
    float step = expf(ls[0]);
    V[(size_t)row * 128] = step * (B[row] + sum);
  }
}

// ---------------- general fp32 GEMM ----------------
// C[M x Nn] = A[M x K] * B[K x Nn] (+D), row-major with ld's.
// flags: 1 = atomicAdd into C (for split-K; C must be pre-zeroed), 2 = add D.
// grid: (ceil(M/64), ceil(Nn/64), KSPLIT); kChunk = K/KSPLIT.
__global__ __launch_bounds__(256) void gemm_k(
    const float* __restrict__ A, int lda,
    const float* __restrict__ Bm, int ldb,
    float* __restrict__ C, int ldc,
    const float* __restrict__ D, int ldd,
    int M, int Nn, int K, int kChunk, int flags) {
  __shared__ __align__(16) float As[16][64];
  __shared__ __align__(16) float Bs[16][64];
  int tid = threadIdx.x;
  int m0 = blockIdx.x * 64, n0 = blockIdx.y * 64;
  int kBegin = blockIdx.z * kChunk;
  int kEnd = kBegin + kChunk; if (kEnd > K) kEnd = K;

  int am = tid >> 2, ak = (tid & 3) << 2;   // A staging: row am, 4 k's
  int bk = tid >> 4, bn = (tid & 15) << 2;  // B staging: row bk, 4 n's
  int ty = tid >> 4, tx = tid & 15;         // compute: 4x4 micro-tile

  bool aOk = (m0 + am) < M;
  const float* Aptr = A + (size_t)(m0 + am) * lda + ak;
  const float* Bptr = Bm + (size_t)bk * ldb + n0 + bn;

  float4 pa = make_float4(0.f, 0.f, 0.f, 0.f);
  if (aOk) pa = *(const float4*)(Aptr + kBegin);
  float4 pb = *(const float4*)(Bptr + (size_t)kBegin * ldb);

  float acc[4][4];
#pragma unroll
  for (int i = 0; i < 4; ++i)
#pragma unroll
    for (int j = 0; j < 4; ++j) acc[i][j] = 0.f;

  for (int kt = kBegin; kt < kEnd; kt += 16) {
    As[ak + 0][am] = pa.x;
    As[ak + 1][am] = pa.y;
    As[ak + 2][am] = pa.z;
    As[ak + 3][am] = pa.w;
    *(float4*)&Bs[bk][bn] = pb;
    __syncthreads();
    int kn = kt + 16;
    if (kn < kEnd) {
      pa = aOk ? *(const float4*)(Aptr + kn) : make_float4(0.f, 0.f, 0.f, 0.f);
      pb = *(const float4*)(Bptr + (size_t)kn * ldb);
    }
#pragma unroll
    for (int k = 0; k < 16; ++k) {
      float4 av = *(const float4*)&As[k][ty << 2];
      float4 bv = *(const float4*)&Bs[k][tx << 2];
      float ar[4] = {av.x, av.y, av.z, av.w};
      float br[4] = {bv.x, bv.y, bv.z, bv.w};
#pragma unroll
      for (int i = 0; i < 4; ++i)
#pragma unroll
        for (int j = 0; j < 4; ++j) acc[i][j] += ar[i] * br[j];
    }
    __syncthreads();
  }

#pragma unroll
  for (int i = 0; i < 4; ++i) {
    int r = m0 + (ty << 2) + i;
    if (r >= M) continue;
#pragma unroll
    for (int j = 0; j < 4; ++j) {
      int c = n0 + (tx << 2) + j;
      if (c >= Nn) continue;
      float v = acc[i][j];
      if (flags & 2) v += D[(size_t)r * ldd + c];
      if (flags & 1) atomicAdd(&C[(size_t)r * ldc + c], v);
      else C[(size_t)r * ldc + c] = v;
    }
  }
}

// ---------------- causal convolution y[t] = sum_{l<=t} K[l] u[t-l] ----------------
// grid (16,16): 1024 outputs per block-x, 1024-tap l-chunk per block-y.
// Zero-padded u window makes causality automatic. atomicAdd into zeroed y.
__global__ __launch_bounds__(256) void conv_k(const float* __restrict__ Kv,
    const float* __restrict__ u, float* __restrict__ y) {
  const int CT = 1024, CJ = 256, LCH = 1024;
  int t0 = blockIdx.x * CT;
  int l0 = blockIdx.y * LCH;
  if (l0 > t0 + CT - 1) return;  // fully non-causal
  __shared__ __align__(16) float Ks[CJ];
  __shared__ __align__(16) float us[CT + CJ + 8];
  int tid = threadIdx.x;
  float acc0 = 0.f, acc1 = 0.f, acc2 = 0.f, acc3 = 0.f;
  int ltEnd = l0 + LCH; if (ltEnd > t0 + CT) ltEnd = t0 + CT;
  for (int lt = l0; lt < ltEnd; lt += CJ) {
    __syncthreads();
    Ks[tid] = Kv[lt + tid];
    int ub = t0 - lt - (CJ - 1);
    for (int s = tid; s < CT + CJ + 4; s += 256) {
      int g = ub + s;
      us[s] = (g >= 0 && g < L_SEQ) ? u[g] : 0.f;
    }
    __syncthreads();
    const float4* u4 = (const float4*)us;
    float4 wa = u4[tid];
#pragma unroll 4
    for (int jb = 0; jb < CJ / 4; ++jb) {
      float4 wb = u4[tid + jb + 1];
      float4 k4 = *(const float4*)&Ks[CJ - 4 - (jb << 2)];
      // acc[c] += Ks[255-(j'+m)] * us[tid*4 + j' + c + m]; k4[3-m] is that K
      acc0 += k4.w * wa.x + k4.z * wa.y + k4.y * wa.z + k4.x * wa.w;
      acc1 += k4.w * wa.y + k4.z * wa.z + k4.y * wa.w + k4.x * wb.x;
      acc2 += k4.w * wa.z + k4.z * wa.w + k4.y * wb.x + k4.x * wb.y;
      acc3 += k4.w * wa.w + k4.z * wb.x + k4.y * wb.y + k4.x * wb.z;
      wa = wb;
    }
  }
  int t = t0 + (tid << 2);
  atomicAdd(&y[t + 0], acc0);
  atomicAdd(&y[t + 1], acc1);
  atomicAdd(&y[t + 2], acc2);
  atomicAdd(&y[t + 3], acc3);
}

// ---------------- host ----------------

extern "C" void kernel_launch(void* const* d_in, const int* in_sizes, int n_in,
                              void* d_out, int out_size, void* d_ws, size_t ws_size,
                              hipStream_t stream) {
  const float* u  = (const float*)d_in[0];
  const float* A  = (const float*)d_in[1];
  const float* B  = (const float*)d_in[2];
  const float* Cm = (const float*)d_in[3];
  const float* ls = (const float*)d_in[4];
  float* y  = (float*)d_out;
  float* ws = (float*)d_ws;

  const int N = N_DIM;
  const size_t NN = (size_t)N * N;
  float* b0 = ws;                 // E -> S
  float* b1 = ws + NN;            // E2 -> ping/pong
  float* b2 = ws + 2 * NN;        // S1 -> Ab -> ping/pong
  float* V  = ws + 3 * NN;        // N x 128 (ld 128)
  float* W  = V + (size_t)N * 128;   // 128 x N (ld N)
  float* Kv = W + (size_t)128 * N;   // L floats

  hipMemsetAsync(V,  0, (size_t)N * 128 * sizeof(float), stream);
  hipMemsetAsync(W,  0, (size_t)128 * N * sizeof(float), stream);
  hipMemsetAsync(Kv, 0, (size_t)L_SEQ * sizeof(float), stream);
  hipMemsetAsync(y,  0, (size_t)L_SEQ * sizeof(float), stream);
  hipMemcpyAsync(W, Cm, N * sizeof(float), hipMemcpyDeviceToDevice, stream); // W row0 = C

  auto gemm = [&](float* C, int ldc, const float* Am, int lda,
                  const float* Bmm, int ldb, const float* D, int ldd,
                  int M, int Nn, int K, int ks, int flags) {
    dim3 g((M + 63) / 64, (Nn + 63) / 64, ks);
    gemm_k<<<g, 256, 0, stream>>>(Am, lda, Bmm, ldb, C, ldc, D, ldd,
                                  M, Nn, K, K / ks, flags);
  };

  // E = (step/2) * A
  k_scaleE<<<NN / 256, 256, 0, stream>>>(b0, A, ls);
  // E2 = E*E
  gemm(b1, N, b0, N, b0, N, nullptr, 0, N, N, N, 1, 0);
  // S1 = E + E2
  k_add<<<NN / 256, 256, 0, stream>>>(b2, b0, b1);
  // S = S1*E2 + S1  (= E+E^2+E^3+E^4)
  gemm(b0, N, b2, N, b1, N, b2, N, N, N, N, 1, 2);
  // Bb -> V[:,0]
  k_bb<<<256, 256, 0, stream>>>(V, b0, B, ls);
  // Ab = I + 2S
  k_mkAb<<<NN / 256, 256, 0, stream>>>(b2, b0);

  // Right Krylov doubling: V[:, s:2s] = Ab^s * V[:, :s]; P -> P^2
  float* cur = b2;  // current power Ab^(2^j)
  float* oth = b1;
  for (int j = 0; j < 7; ++j) {
    int s = 1 << j;
    gemm(V + s, 128, cur, N, V, 128, nullptr, 0, N, s, N, 8, 1);
    gemm(oth, N, cur, N, cur, N, nullptr, 0, N, N, N, 1, 0);
    float* t = cur; cur = oth; oth = t;
  }
  // cur = Ab^128. Left Krylov doubling: W[r:2r,:] = W[:r,:] * Q; Q -> Q^2
  for (int j = 0; j < 7; ++j) {
    int r = 1 << j;
    gemm(W + (size_t)r * N, N, W, N, cur, N, nullptr, 0, r, N, N, 8, 1);
    if (j < 6) {
      gemm(oth, N, cur, N, cur, N, nullptr, 0, N, N, N, 1, 0);
      float* t = cur; cur = oth; oth = t;
    }
  }
  // K[128q + r] = W[q,:] . V[:,r]
  gemm(Kv, 128, W, N, V, 128, nullptr, 0, 128, 128, N, 8, 1);
  // y = causal conv(K, u)
  conv_k<<<dim3(16, 16), 256, 0, stream>>>(Kv, u, y);
}

// Round 2
// 804.178 us; speedup vs baseline: 1.1280x; 1.1280x over previous
//
#include <hip/hip_runtime.h>
#include <hip/hip_bf16.h>
#include <math.h>

#define N_DIM 1024
#define L_SEQ 16384

typedef unsigned short ushort_t;
typedef __bf16 bf16x8 __attribute__((ext_vector_type(8)));
typedef float f32x4 __attribute__((ext_vector_type(4)));

#define FW_F32 1
#define FW_SPLIT 2
#define FW_TSPLIT 4
#define FW_ADDD 8

__device__ __forceinline__ void split3(float v, ushort_t& h, ushort_t& m, ushort_t& l) {
  union { __bf16 b; ushort_t u; } c;
  __bf16 bh = (__bf16)v; float fh = (float)bh;
  float r1 = v - fh;
  __bf16 bm = (__bf16)r1; float fm = (float)bm;
  __bf16 bl = (__bf16)(r1 - fm);
  c.b = bh; h = c.u; c.b = bm; m = c.u; c.b = bl; l = c.u;
}

// ---------------- elementwise helpers ----------------

__global__ __launch_bounds__(256) void k_scaleE(float* __restrict__ E,
    const float* __restrict__ A, const float* __restrict__ ls) {
  int i = blockIdx.x * 256 + threadIdx.x;
  float h = 0.5f * expf(ls[0]);
  E[i] = h * A[i];
}

__global__ __launch_bounds__(256) void k_add(float* __restrict__ out,
    const float* __restrict__ a, const float* __restrict__ b) {
  int i = blockIdx.x * 256 + threadIdx.x;
  out[i] = a[i] + b[i];
}

__global__ __launch_bounds__(256) void k_mkAb(float* __restrict__ out,
    const float* __restrict__ S) {
  int i = blockIdx.x * 256 + threadIdx.x;
  int row = i >> 10, col = i & (N_DIM - 1);
  out[i] = 2.0f * S[i] + ((row == col) ? 1.0f : 0.0f);
}

__global__ __launch_bounds__(256) void k_bb(float* __restrict__ V,
    const float* __restrict__ S, const float* __restrict__ B,
    const float* __restrict__ ls) {
  int row = blockIdx.x * 4 + (threadIdx.x >> 6);
  int lane = threadIdx.x & 63;
  const float* Sr = S + (size_t)row * N_DIM;
  float sum = 0.f;
  for (int k = lane; k < N_DIM; k += 64) sum += Sr[k] * B[k];
  for (int off = 32; off; off >>= 1) sum += __shfl_down(sum, off);
  if (lane == 0) {
    float step = expf(ls[0]);
    V[(size_t)row * 128] = step * (B[row] + sum);
  }
}

// ---------------- split: fp32 X -> {H,M,L, HT,MT,LT} bf16 (each NN) -------
__global__ __launch_bounds__(256) void k_split(const float* __restrict__ X,
                                               ushort_t* __restrict__ set) {
  const size_t NN = (size_t)N_DIM * N_DIM;
  int t = threadIdx.x;
  int r0 = blockIdx.x * 64 + ((t >> 4) << 2);
  int c0 = blockIdx.y * 64 + ((t & 15) << 2);
  float v[4][4];
#pragma unroll
  for (int i = 0; i < 4; ++i) {
    float4 f = *(const float4*)&X[(size_t)(r0 + i) * N_DIM + c0];
    v[i][0] = f.x; v[i][1] = f.y; v[i][2] = f.z; v[i][3] = f.w;
  }
  ushort_t h[4][4], m[4][4], l[4][4];
#pragma unroll
  for (int i = 0; i < 4; ++i)
#pragma unroll
    for (int j = 0; j < 4; ++j) split3(v[i][j], h[i][j], m[i][j], l[i][j]);
  ushort_t* H = set;           ushort_t* M = set + NN;      ushort_t* L = set + 2 * NN;
  ushort_t* HT = set + 3 * NN; ushort_t* MT = set + 4 * NN; ushort_t* LT = set + 5 * NN;
#pragma unroll
  for (int i = 0; i < 4; ++i) {
    size_t o = (size_t)(r0 + i) * N_DIM + c0;
    *(ushort4*)&H[o] = make_ushort4(h[i][0], h[i][1], h[i][2], h[i][3]);
    *(ushort4*)&M[o] = make_ushort4(m[i][0], m[i][1], m[i][2], m[i][3]);
    *(ushort4*)&L[o] = make_ushort4(l[i][0], l[i][1], l[i][2], l[i][3]);
  }
#pragma unroll
  for (int j = 0; j < 4; ++j) {
    size_t o = (size_t)(c0 + j) * N_DIM + r0;
    *(ushort4*)&HT[o] = make_ushort4(h[0][j], h[1][j], h[2][j], h[3][j]);
    *(ushort4*)&MT[o] = make_ushort4(m[0][j], m[1][j], m[2][j], m[3][j]);
    *(ushort4*)&LT[o] = make_ushort4(l[0][j], l[1][j], l[2][j], l[3][j]);
  }
}

// ---------------- bf16x6 split-compensated 1024^3 GEMM --------------------
// C = A*B (+D). Aset = {Ah,Am,Al} row-major MxK; Bset = {BTh,BTm,BTl} NxK
// (i.e. B transposed, row-major). Oset gets C's splits (+transposed splits).
__global__ __launch_bounds__(256) void gemm6(
    const ushort_t* __restrict__ Aset, const ushort_t* __restrict__ Bset,
    float* __restrict__ C, const float* __restrict__ D,
    ushort_t* __restrict__ Oset, int flags) {
  // LDS: [2 buf][6 levels: Ah,Am,Al,Bh,Bm,Bl][4 kc][64 rows][8 bf16]
  __shared__ __align__(16) ushort_t lds[2][6][2048];
  const size_t NN = (size_t)N_DIM * N_DIM;
  int t = threadIdx.x;
  int m0 = blockIdx.x * 64, n0 = blockIdx.y * 64;
  int r = t & 63, kc = t >> 6;

  const ushort_t* gA[3] = {Aset, Aset + NN, Aset + 2 * NN};
  const ushort_t* gB[3] = {Bset, Bset + NN, Bset + 2 * NN};
  size_t aoff = (size_t)(m0 + r) * N_DIM + kc * 8;
  size_t boff = (size_t)(n0 + r) * N_DIM + kc * 8;

  auto stage = [&](int buf, int k0) {
    ushort_t* dst = &lds[buf][0][0];
#pragma unroll
    for (int L = 0; L < 3; ++L)
      __builtin_amdgcn_global_load_lds(
          (const __attribute__((address_space(1))) void*)(gA[L] + aoff + k0),
          (__attribute__((address_space(3))) void*)(dst + L * 2048 + t * 8), 16, 0, 0);
#pragma unroll
    for (int L = 0; L < 3; ++L)
      __builtin_amdgcn_global_load_lds(
          (const __attribute__((address_space(1))) void*)(gB[L] + boff + k0),
          (__attribute__((address_space(3))) void*)(dst + (3 + L) * 2048 + t * 8), 16, 0, 0);
  };

  f32x4 acc[2][2];
#pragma unroll
  for (int i = 0; i < 2; ++i)
#pragma unroll
    for (int j = 0; j < 2; ++j) acc[i][j] = (f32x4){0.f, 0.f, 0.f, 0.f};

  const int lane = t & 63, w = t >> 6;
  const int wm = (w >> 1) * 32, wn = (w & 1) * 32;
  const int lrow = lane & 15, kg = lane >> 4;
  const int aIdx0 = kg * 512 + (wm + lrow) * 8;
  const int bIdx0 = 3 * 2048 + kg * 512 + (wn + lrow) * 8;

  stage(0, 0);
  __syncthreads();
  for (int ks = 0; ks < 32; ++ks) {
    int cur = ks & 1;
    if (ks < 31) stage(cur ^ 1, (ks + 1) * 32);
    const ushort_t* buf = &lds[cur][0][0];
    bf16x8 a[3][2], b[3][2];
#pragma unroll
    for (int L = 0; L < 3; ++L) {
#pragma unroll
      for (int mi = 0; mi < 2; ++mi)
        a[L][mi] = *(const bf16x8*)&buf[L * 2048 + aIdx0 + mi * 128];
#pragma unroll
      for (int ni = 0; ni < 2; ++ni)
        b[L][ni] = *(const bf16x8*)&buf[bIdx0 + L * 2048 + ni * 128];
    }
#pragma unroll
    for (int mi = 0; mi < 2; ++mi)
#pragma unroll
      for (int ni = 0; ni < 2; ++ni) {
        f32x4 c = acc[mi][ni];
        c = __builtin_amdgcn_mfma_f32_16x16x32_bf16(a[0][mi], b[0][ni], c, 0, 0, 0);
        c = __builtin_amdgcn_mfma_f32_16x16x32_bf16(a[0][mi], b[1][ni], c, 0, 0, 0);
        c = __builtin_amdgcn_mfma_f32_16x16x32_bf16(a[1][mi], b[0][ni], c, 0, 0, 0);
        c = __builtin_amdgcn_mfma_f32_16x16x32_bf16(a[0][mi], b[2][ni], c, 0, 0, 0);
        c = __builtin_amdgcn_mfma_f32_16x16x32_bf16(a[2][mi], b[0][ni], c, 0, 0, 0);
        c = __builtin_amdgcn_mfma_f32_16x16x32_bf16(a[1][mi], b[1][ni], c, 0, 0, 0);
        acc[mi][ni] = c;
      }
    __syncthreads();
  }

  // ---- epilogue: fp32 C (+D) and/or split outputs ----
  ushort_t* OH = Oset;            ushort_t* OM = Oset + NN;     ushort_t* OL = Oset + 2 * NN;
  ushort_t* OTH = Oset + 3 * NN;  ushort_t* OTM = Oset + 4 * NN; ushort_t* OTL = Oset + 5 * NN;
#pragma unroll
  for (int mi = 0; mi < 2; ++mi)
#pragma unroll
    for (int ni = 0; ni < 2; ++ni) {
      int rowb = m0 + wm + mi * 16 + kg * 4;
      int col = n0 + wn + ni * 16 + lrow;
      float vv[4];
#pragma unroll
      for (int j = 0; j < 4; ++j) {
        vv[j] = acc[mi][ni][j];
        if (flags & FW_ADDD) vv[j] += D[(size_t)(rowb + j) * N_DIM + col];
        if (flags & FW_F32) C[(size_t)(rowb + j) * N_DIM + col] = vv[j];
      }
      if (flags & (FW_SPLIT | FW_TSPLIT)) {
        ushort_t h[4], m[4], l[4];
#pragma unroll
        for (int j = 0; j < 4; ++j) split3(vv[j], h[j], m[j], l[j]);
        if (flags & FW_SPLIT) {
#pragma unroll
          for (int j = 0; j < 4; ++j) {
            size_t o = (size_t)(rowb + j) * N_DIM + col;
            OH[o] = h[j]; OM[o] = m[j]; OL[o] = l[j];
          }
        }
        if (flags & FW_TSPLIT) {
          size_t o = (size_t)col * N_DIM + rowb;
          *(ushort4*)&OTH[o] = make_ushort4(h[0], h[1], h[2], h[3]);
          *(ushort4*)&OTM[o] = make_ushort4(m[0], m[1], m[2], m[3]);
          *(ushort4*)&OTL[o] = make_ushort4(l[0], l[1], l[2], l[3]);
        }
      }
    }
}

// ---------------- general fp32 GEMM (skinny Krylov ops) -------------------
__global__ __launch_bounds__(256) void gemm_k(
    const float* __restrict__ A, int lda,
    const float* __restrict__ Bm, int ldb,
    float* __restrict__ C, int ldc,
    const float* __restrict__ D, int ldd,
    int M, int Nn, int K, int kChunk, int flags) {
  __shared__ __align__(16) float As[16][64];
  __shared__ __align__(16) float Bs[16][64];
  int tid = threadIdx.x;
  int m0 = blockIdx.x * 64, n0 = blockIdx.y * 64;
  int kBegin = blockIdx.z * kChunk;
  int kEnd = kBegin + kChunk; if (kEnd > K) kEnd = K;

  int am = tid >> 2, ak = (tid & 3) << 2;
  int bk = tid >> 4, bn = (tid & 15) << 2;
  int ty = tid >> 4, tx = tid & 15;

  bool aOk = (m0 + am) < M;
  const float* Aptr = A + (size_t)(m0 + am) * lda + ak;
  const float* Bptr = Bm + (size_t)bk * ldb + n0 + bn;

  float4 pa = make_float4(0.f, 0.f, 0.f, 0.f);
  if (aOk) pa = *(const float4*)(Aptr + kBegin);
  float4 pb = *(const float4*)(Bptr + (size_t)kBegin * ldb);

  float acc[4][4];
#pragma unroll
  for (int i = 0; i < 4; ++i)
#pragma unroll
    for (int j = 0; j < 4; ++j) acc[i][j] = 0.f;

  for (int kt = kBegin; kt < kEnd; kt += 16) {
    As[ak + 0][am] = pa.x;
    As[ak + 1][am] = pa.y;
    As[ak + 2][am] = pa.z;
    As[ak + 3][am] = pa.w;
    *(float4*)&Bs[bk][bn] = pb;
    __syncthreads();
    int kn = kt + 16;
    if (kn < kEnd) {
      pa = aOk ? *(const float4*)(Aptr + kn) : make_float4(0.f, 0.f, 0.f, 0.f);
      pb = *(const float4*)(Bptr + (size_t)kn * ldb);
    }
#pragma unroll
    for (int k = 0; k < 16; ++k) {
      float4 av = *(const float4*)&As[k][ty << 2];
      float4 bv = *(const float4*)&Bs[k][tx << 2];
      float ar[4] = {av.x, av.y, av.z, av.w};
      float br[4] = {bv.x, bv.y, bv.z, bv.w};
#pragma unroll
      for (int i = 0; i < 4; ++i)
#pragma unroll
        for (int j = 0; j < 4; ++j) acc[i][j] += ar[i] * br[j];
    }
    __syncthreads();
  }

#pragma unroll
  for (int i = 0; i < 4; ++i) {
    int rr = m0 + (ty << 2) + i;
    if (rr >= M) continue;
#pragma unroll
    for (int j = 0; j < 4; ++j) {
      int c = n0 + (tx << 2) + j;
      if (c >= Nn) continue;
      float v = acc[i][j];
      if (flags & 2) v += D[(size_t)rr * ldd + c];
      if (flags & 1) atomicAdd(&C[(size_t)rr * ldc + c], v);
      else C[(size_t)rr * ldc + c] = v;
    }
  }
}

// ---------------- causal convolution --------------------------------------
__global__ __launch_bounds__(256) void conv_k(const float* __restrict__ Kv,
    const float* __restrict__ u, float* __restrict__ y) {
  const int CT = 1024, CJ = 256, LCH = 1024;
  int t0 = blockIdx.x * CT;
  int l0 = blockIdx.y * LCH;
  if (l0 > t0 + CT - 1) return;
  __shared__ __align__(16) float Ks[CJ];
  __shared__ __align__(16) float us[CT + CJ + 8];
  int tid = threadIdx.x;
  float acc0 = 0.f, acc1 = 0.f, acc2 = 0.f, acc3 = 0.f;
  int ltEnd = l0 + LCH; if (ltEnd > t0 + CT) ltEnd = t0 + CT;
  for (int lt = l0; lt < ltEnd; lt += CJ) {
    __syncthreads();
    Ks[tid] = Kv[lt + tid];
    int ub = t0 - lt - (CJ - 1);
    for (int s = tid; s < CT + CJ + 4; s += 256) {
      int g = ub + s;
      us[s] = (g >= 0 && g < L_SEQ) ? u[g] : 0.f;
    }
    __syncthreads();
    const float4* u4 = (const float4*)us;
    float4 wa = u4[tid];
#pragma unroll 4
    for (int jb = 0; jb < CJ / 4; ++jb) {
      float4 wb = u4[tid + jb + 1];
      float4 k4 = *(const float4*)&Ks[CJ - 4 - (jb << 2)];
      acc0 += k4.w * wa.x + k4.z * wa.y + k4.y * wa.z + k4.x * wa.w;
      acc1 += k4.w * wa.y + k4.z * wa.z + k4.y * wa.w + k4.x * wb.x;
      acc2 += k4.w * wa.z + k4.z * wa.w + k4.y * wb.x + k4.x * wb.y;
      acc3 += k4.w * wa.w + k4.z * wb.x + k4.y * wb.y + k4.x * wb.z;
      wa = wb;
    }
  }
  int t = t0 + (tid << 2);
  atomicAdd(&y[t + 0], acc0);
  atomicAdd(&y[t + 1], acc1);
  atomicAdd(&y[t + 2], acc2);
  atomicAdd(&y[t + 3], acc3);
}

// ---------------- host ----------------

extern "C" void kernel_launch(void* const* d_in, const int* in_sizes, int n_in,
                              void* d_out, int out_size, void* d_ws, size_t ws_size,
                              hipStream_t stream) {
  const float* u  = (const float*)d_in[0];
  const float* A  = (const float*)d_in[1];
  const float* B  = (const float*)d_in[2];
  const float* Cm = (const float*)d_in[3];
  const float* ls = (const float*)d_in[4];
  float* y  = (float*)d_out;
  float* ws = (float*)d_ws;

  const int N = N_DIM;
  const size_t NN = (size_t)N * N;
  float* b0 = ws;
  float* b1 = ws + NN;
  float* b2 = ws + 2 * NN;
  float* V  = ws + 3 * NN;
  float* W  = V + (size_t)N * 128;
  float* Kv = W + (size_t)128 * N;
  ushort_t* setA = (ushort_t*)(Kv + L_SEQ);
  ushort_t* setB = setA + 6 * NN;

  hipMemsetAsync(V,  0, (size_t)N * 128 * sizeof(float), stream);
  hipMemsetAsync(W,  0, (size_t)128 * N * sizeof(float), stream);
  hipMemsetAsync(Kv, 0, (size_t)L_SEQ * sizeof(float), stream);
  hipMemsetAsync(y,  0, (size_t)L_SEQ * sizeof(float), stream);
  hipMemcpyAsync(W, Cm, N * sizeof(float), hipMemcpyDeviceToDevice, stream);

  dim3 g16(16, 16);
  auto gemm = [&](float* C, int ldc, const float* Am, int lda,
                  const float* Bmm, int ldb, const float* D, int ldd,
                  int M, int Nn, int K, int ks, int flags) {
    dim3 g((M + 63) / 64, (Nn + 63) / 64, ks);
    gemm_k<<<g, 256, 0, stream>>>(Am, lda, Bmm, ldb, C, ldc, D, ldd,
                                  M, Nn, K, K / ks, flags);
  };

  // E = (step/2)*A ; splits of E
  k_scaleE<<<NN / 256, 256, 0, stream>>>(b0, A, ls);
  k_split<<<g16, 256, 0, stream>>>(b0, setA);
  // E2 = E*E  (fp32 -> b1, transposed splits -> setB[3..5])
  gemm6<<<g16, 256, 0, stream>>>(setA, setA + 3 * NN, b1, nullptr, setB,
                                 FW_F32 | FW_TSPLIT);
  // S1 = E + E2 ; splits of S1
  k_add<<<NN / 256, 256, 0, stream>>>(b2, b0, b1);
  k_split<<<g16, 256, 0, stream>>>(b2, setA);
  // S = S1*E2 + S1  (fp32 -> b0)
  gemm6<<<g16, 256, 0, stream>>>(setA, setB + 3 * NN, b0, b2, setB, FW_F32 | FW_ADDD);
  // Bb -> V[:,0] ; Ab = I + 2S -> b1 ; splits of Ab
  k_bb<<<256, 256, 0, stream>>>(V, b0, B, ls);
  k_mkAb<<<NN / 256, 256, 0, stream>>>(b1, b0);
  k_split<<<g16, 256, 0, stream>>>(b1, setA);

  float* curf = b1;
  float* freef[2] = {b2, b0};
  int ff = 0;
  ushort_t* curs = setA;
  ushort_t* oths = setB;

  // Right Krylov doubling: V[:, s:2s] = Ab^s * V[:, :s]; square the power.
  for (int j = 0; j < 7; ++j) {
    int s = 1 << j;
    gemm(V + s, 128, curf, N, V, 128, nullptr, 0, N, s, N, 8, 1);
    float* nf = freef[ff];
    gemm6<<<g16, 256, 0, stream>>>(curs, curs + 3 * NN, nf, nullptr, oths,
                                   FW_F32 | FW_SPLIT | FW_TSPLIT);
    freef[ff] = curf; curf = nf; ff ^= 1;
    ushort_t* tmp = curs; curs = oths; oths = tmp;
  }
  // Left Krylov doubling: W[r:2r,:] = W[:r,:] * Q; square Q.
  for (int j = 0; j < 7; ++j) {
    int rr = 1 << j;
    gemm(W + (size_t)rr * N, N, W, N, curf, N, nullptr, 0, rr, N, N, 8, 1);
    if (j < 6) {
      float* nf = freef[ff];
      int fl = (j == 5) ? FW_F32 : (FW_F32 | FW_SPLIT | FW_TSPLIT);
      gemm6<<<g16, 256, 0, stream>>>(curs, curs + 3 * NN, nf, nullptr, oths, fl);
      freef[ff] = curf; curf = nf; ff ^= 1;
      ushort_t* tmp = curs; curs = oths; oths = tmp;
    }
  }
  // K[128q + r] = W[q,:] . V[:,r]
  gemm(Kv, 128, W, N, V, 128, nullptr, 0, 128, 128, N, 8, 1);
  // y = causal conv(K, u)
  conv_k<<<dim3(16, 16), 256, 0, stream>>>(Kv, u, y);
}

// Round 3
// 636.809 us; speedup vs baseline: 1.4245x; 1.2628x over previous
//
#include <hip/hip_runtime.h>
#include <hip/hip_bf16.h>
#include <math.h>

#define N_DIM 1024
#define L_SEQ 16384
#define NPART 4

typedef unsigned short ushort_t;
typedef __bf16 bf16x8 __attribute__((ext_vector_type(8)));
typedef float f32x4 __attribute__((ext_vector_type(4)));

#define FW_F32 1
#define FW_SPLIT 2
#define FW_TSPLIT 4
#define FW_ADDD 8

__device__ __forceinline__ void split2(float v, ushort_t& h, ushort_t& m) {
  union { __bf16 b; ushort_t u; } c;
  __bf16 bh = (__bf16)v;
  float fh = (float)bh;
  c.b = bh; h = c.u;
  c.b = (__bf16)(v - fh); m = c.u;
}

// ---------------- elementwise helpers ----------------

__global__ __launch_bounds__(256) void k_scaleE(float* __restrict__ E,
    const float* __restrict__ A, const float* __restrict__ ls) {
  int i = blockIdx.x * 256 + threadIdx.x;
  float h = 0.5f * expf(ls[0]);
  E[i] = h * A[i];
}

__global__ __launch_bounds__(256) void k_add(float* __restrict__ out,
    const float* __restrict__ a, const float* __restrict__ b) {
  int i = blockIdx.x * 256 + threadIdx.x;
  out[i] = a[i] + b[i];
}

__global__ __launch_bounds__(256) void k_mkAb(float* __restrict__ out,
    const float* __restrict__ S) {
  int i = blockIdx.x * 256 + threadIdx.x;
  int row = i >> 10, col = i & (N_DIM - 1);
  out[i] = 2.0f * S[i] + ((row == col) ? 1.0f : 0.0f);
}

__global__ __launch_bounds__(256) void k_bb(float* __restrict__ V,
    const float* __restrict__ S, const float* __restrict__ B,
    const float* __restrict__ ls) {
  int row = blockIdx.x * 4 + (threadIdx.x >> 6);
  int lane = threadIdx.x & 63;
  const float* Sr = S + (size_t)row * N_DIM;
  float sum = 0.f;
  for (int k = lane; k < N_DIM; k += 64) sum += Sr[k] * B[k];
  for (int off = 32; off; off >>= 1) sum += __shfl_down(sum, off);
  if (lane == 0) {
    float step = expf(ls[0]);
    V[(size_t)row * 128] = step * (B[row] + sum);
  }
}

// ------- reduce NPART partials (+D), write fp32 and/or 2-splits (+T) -------
// set layout: {H, M, HT, MT}, each NN ushorts.
__global__ __launch_bounds__(256) void k_splitred(
    const float* __restrict__ P, int nparts,
    const float* __restrict__ D, float* __restrict__ Cf,
    ushort_t* __restrict__ set, int flags) {
  const size_t NN = (size_t)N_DIM * N_DIM;
  int t = threadIdx.x;
  int r0 = blockIdx.x * 64 + ((t >> 4) << 2);
  int c0 = blockIdx.y * 64 + ((t & 15) << 2);
  float v[4][4];
#pragma unroll
  for (int i = 0; i < 4; ++i) {
    float4 f = *(const float4*)&P[(size_t)(r0 + i) * N_DIM + c0];
    v[i][0] = f.x; v[i][1] = f.y; v[i][2] = f.z; v[i][3] = f.w;
  }
  for (int p = 1; p < nparts; ++p) {
#pragma unroll
    for (int i = 0; i < 4; ++i) {
      float4 f = *(const float4*)&P[p * NN + (size_t)(r0 + i) * N_DIM + c0];
      v[i][0] += f.x; v[i][1] += f.y; v[i][2] += f.z; v[i][3] += f.w;
    }
  }
  if (flags & FW_ADDD) {
#pragma unroll
    for (int i = 0; i < 4; ++i) {
      float4 f = *(const float4*)&D[(size_t)(r0 + i) * N_DIM + c0];
      v[i][0] += f.x; v[i][1] += f.y; v[i][2] += f.z; v[i][3] += f.w;
    }
  }
  if (flags & FW_F32) {
#pragma unroll
    for (int i = 0; i < 4; ++i)
      *(float4*)&Cf[(size_t)(r0 + i) * N_DIM + c0] =
          make_float4(v[i][0], v[i][1], v[i][2], v[i][3]);
  }
  if (flags & (FW_SPLIT | FW_TSPLIT)) {
    ushort_t h[4][4], m[4][4];
#pragma unroll
    for (int i = 0; i < 4; ++i)
#pragma unroll
      for (int j = 0; j < 4; ++j) split2(v[i][j], h[i][j], m[i][j]);
    ushort_t* H = set;           ushort_t* M = set + NN;
    ushort_t* HT = set + 2 * NN; ushort_t* MT = set + 3 * NN;
    if (flags & FW_SPLIT) {
#pragma unroll
      for (int i = 0; i < 4; ++i) {
        size_t o = (size_t)(r0 + i) * N_DIM + c0;
        *(ushort4*)&H[o] = make_ushort4(h[i][0], h[i][1], h[i][2], h[i][3]);
        *(ushort4*)&M[o] = make_ushort4(m[i][0], m[i][1], m[i][2], m[i][3]);
      }
    }
    if (flags & FW_TSPLIT) {
#pragma unroll
      for (int j = 0; j < 4; ++j) {
        size_t o = (size_t)(c0 + j) * N_DIM + r0;
        *(ushort4*)&HT[o] = make_ushort4(h[0][j], h[1][j], h[2][j], h[3][j]);
        *(ushort4*)&MT[o] = make_ushort4(m[0][j], m[1][j], m[2][j], m[3][j]);
      }
    }
  }
}

// ---------------- bf16 2-split 4-product GEMM, split-K -------------------
// P[kz] = A*B over K-chunk kz. Aset = {Ah,Am} row-major; Bset = {BTh,BTm}.
// grid (16, 16, NPART), 256 threads.
__global__ __launch_bounds__(256) void gemm4(
    const ushort_t* __restrict__ Aset, const ushort_t* __restrict__ Bset,
    float* __restrict__ P, int kChunk) {
  __shared__ __align__(16) ushort_t lds[2][4][2048];
  const size_t NN = (size_t)N_DIM * N_DIM;
  int t = threadIdx.x;
  int m0 = blockIdx.x * 64, n0 = blockIdx.y * 64;
  int kz = blockIdx.z;
  int r = t & 63, kc = t >> 6;

  const ushort_t* gA[2] = {Aset, Aset + NN};
  const ushort_t* gB[2] = {Bset, Bset + NN};
  size_t aoff = (size_t)(m0 + r) * N_DIM + kc * 8 + (size_t)kz * kChunk;
  size_t boff = (size_t)(n0 + r) * N_DIM + kc * 8 + (size_t)kz * kChunk;

  auto stage = [&](int buf, int k0) {
    ushort_t* dst = &lds[buf][0][0];
#pragma unroll
    for (int L = 0; L < 2; ++L) {
      __builtin_amdgcn_global_load_lds(
          (const __attribute__((address_space(1))) void*)(gA[L] + aoff + k0),
          (__attribute__((address_space(3))) void*)(dst + L * 2048 + t * 8), 16, 0, 0);
      __builtin_amdgcn_global_load_lds(
          (const __attribute__((address_space(1))) void*)(gB[L] + boff + k0),
          (__attribute__((address_space(3))) void*)(dst + (2 + L) * 2048 + t * 8), 16, 0, 0);
    }
  };

  f32x4 acc[2][2];
#pragma unroll
  for (int i = 0; i < 2; ++i)
#pragma unroll
    for (int j = 0; j < 2; ++j) acc[i][j] = (f32x4){0.f, 0.f, 0.f, 0.f};

  const int lane = t & 63, w = t >> 6;
  const int wm = (w >> 1) * 32, wn = (w & 1) * 32;
  const int lrow = lane & 15, kg = lane >> 4;
  const int aIdx0 = kg * 512 + (wm + lrow) * 8;
  const int bIdx0 = 2 * 2048 + kg * 512 + (wn + lrow) * 8;

  stage(0, 0);
  __syncthreads();
  int nSteps = kChunk >> 5;
  for (int ks = 0; ks < nSteps; ++ks) {
    int cur = ks & 1;
    if (ks < nSteps - 1) stage(cur ^ 1, (ks + 1) * 32);
    const ushort_t* buf = &lds[cur][0][0];
    bf16x8 a[2][2], b[2][2];
#pragma unroll
    for (int L = 0; L < 2; ++L) {
#pragma unroll
      for (int mi = 0; mi < 2; ++mi)
        a[L][mi] = *(const bf16x8*)&buf[L * 2048 + aIdx0 + mi * 128];
#pragma unroll
      for (int ni = 0; ni < 2; ++ni)
        b[L][ni] = *(const bf16x8*)&buf[bIdx0 + L * 2048 + ni * 128];
    }
#pragma unroll
    for (int mi = 0; mi < 2; ++mi)
#pragma unroll
      for (int ni = 0; ni < 2; ++ni) {
        f32x4 c = acc[mi][ni];
        c = __builtin_amdgcn_mfma_f32_16x16x32_bf16(a[0][mi], b[0][ni], c, 0, 0, 0);
        c = __builtin_amdgcn_mfma_f32_16x16x32_bf16(a[0][mi], b[1][ni], c, 0, 0, 0);
        c = __builtin_amdgcn_mfma_f32_16x16x32_bf16(a[1][mi], b[0][ni], c, 0, 0, 0);
        c = __builtin_amdgcn_mfma_f32_16x16x32_bf16(a[1][mi], b[1][ni], c, 0, 0, 0);
        acc[mi][ni] = c;
      }
    __syncthreads();
  }

  float* Pk = P + (size_t)kz * NN;
#pragma unroll
  for (int mi = 0; mi < 2; ++mi)
#pragma unroll
    for (int ni = 0; ni < 2; ++ni) {
      int rowb = m0 + wm + mi * 16 + kg * 4;
      int col = n0 + wn + ni * 16 + lrow;
#pragma unroll
      for (int j = 0; j < 4; ++j)
        Pk[(size_t)(rowb + j) * N_DIM + col] = acc[mi][ni][j];
    }
}

// ---------------- general fp32 GEMM (skinny Krylov ops) -------------------
__global__ __launch_bounds__(256) void gemm_k(
    const float* __restrict__ A, int lda,
    const float* __restrict__ Bm, int ldb,
    float* __restrict__ C, int ldc,
    const float* __restrict__ D, int ldd,
    int M, int Nn, int K, int kChunk, int flags) {
  __shared__ __align__(16) float As[16][64];
  __shared__ __align__(16) float Bs[16][64];
  int tid = threadIdx.x;
  int m0 = blockIdx.x * 64, n0 = blockIdx.y * 64;
  int kBegin = blockIdx.z * kChunk;
  int kEnd = kBegin + kChunk; if (kEnd > K) kEnd = K;

  int am = tid >> 2, ak = (tid & 3) << 2;
  int bk = tid >> 4, bn = (tid & 15) << 2;
  int ty = tid >> 4, tx = tid & 15;

  bool aOk = (m0 + am) < M;
  const float* Aptr = A + (size_t)(m0 + am) * lda + ak;
  const float* Bptr = Bm + (size_t)bk * ldb + n0 + bn;

  float4 pa = make_float4(0.f, 0.f, 0.f, 0.f);
  if (aOk) pa = *(const float4*)(Aptr + kBegin);
  float4 pb = *(const float4*)(Bptr + (size_t)kBegin * ldb);

  float acc[4][4];
#pragma unroll
  for (int i = 0; i < 4; ++i)
#pragma unroll
    for (int j = 0; j < 4; ++j) acc[i][j] = 0.f;

  for (int kt = kBegin; kt < kEnd; kt += 16) {
    As[ak + 0][am] = pa.x;
    As[ak + 1][am] = pa.y;
    As[ak + 2][am] = pa.z;
    As[ak + 3][am] = pa.w;
    *(float4*)&Bs[bk][bn] = pb;
    __syncthreads();
    int kn = kt + 16;
    if (kn < kEnd) {
      pa = aOk ? *(const float4*)(Aptr + kn) : make_float4(0.f, 0.f, 0.f, 0.f);
      pb = *(const float4*)(Bptr + (size_t)kn * ldb);
    }
#pragma unroll
    for (int k = 0; k < 16; ++k) {
      float4 av = *(const float4*)&As[k][ty << 2];
      float4 bv = *(const float4*)&Bs[k][tx << 2];
      float ar[4] = {av.x, av.y, av.z, av.w};
      float br[4] = {bv.x, bv.y, bv.z, bv.w};
#pragma unroll
      for (int i = 0; i < 4; ++i)
#pragma unroll
        for (int j = 0; j < 4; ++j) acc[i][j] += ar[i] * br[j];
    }
    __syncthreads();
  }

#pragma unroll
  for (int i = 0; i < 4; ++i) {
    int rr = m0 + (ty << 2) + i;
    if (rr >= M) continue;
#pragma unroll
    for (int j = 0; j < 4; ++j) {
      int c = n0 + (tx << 2) + j;
      if (c >= Nn) continue;
      float v = acc[i][j];
      if (flags & 2) v += D[(size_t)rr * ldd + c];
      if (flags & 1) atomicAdd(&C[(size_t)rr * ldc + c], v);
      else C[(size_t)rr * ldc + c] = v;
    }
  }
}

// ---------------- causal convolution --------------------------------------
__global__ __launch_bounds__(256) void conv_k(const float* __restrict__ Kv,
    const float* __restrict__ u, float* __restrict__ y) {
  const int CT = 1024, CJ = 256, LCH = 1024;
  int t0 = blockIdx.x * CT;
  int l0 = blockIdx.y * LCH;
  if (l0 > t0 + CT - 1) return;
  __shared__ __align__(16) float Ks[CJ];
  __shared__ __align__(16) float us[CT + CJ + 8];
  int tid = threadIdx.x;
  float acc0 = 0.f, acc1 = 0.f, acc2 = 0.f, acc3 = 0.f;
  int ltEnd = l0 + LCH; if (ltEnd > t0 + CT) ltEnd = t0 + CT;
  for (int lt = l0; lt < ltEnd; lt += CJ) {
    __syncthreads();
    Ks[tid] = Kv[lt + tid];
    int ub = t0 - lt - (CJ - 1);
    for (int s = tid; s < CT + CJ + 4; s += 256) {
      int g = ub + s;
      us[s] = (g >= 0 && g < L_SEQ) ? u[g] : 0.f;
    }
    __syncthreads();
    const float4* u4 = (const float4*)us;
    float4 wa = u4[tid];
#pragma unroll 4
    for (int jb = 0; jb < CJ / 4; ++jb) {
      float4 wb = u4[tid + jb + 1];
      float4 k4 = *(const float4*)&Ks[CJ - 4 - (jb << 2)];
      acc0 += k4.w * wa.x + k4.z * wa.y + k4.y * wa.z + k4.x * wa.w;
      acc1 += k4.w * wa.y + k4.z * wa.z + k4.y * wa.w + k4.x * wb.x;
      acc2 += k4.w * wa.z + k4.z * wa.w + k4.y * wb.x + k4.x * wb.y;
      acc3 += k4.w * wa.w + k4.z * wb.x + k4.y * wb.y + k4.x * wb.z;
      wa = wb;
    }
  }
  int t = t0 + (tid << 2);
  atomicAdd(&y[t + 0], acc0);
  atomicAdd(&y[t + 1], acc1);
  atomicAdd(&y[t + 2], acc2);
  atomicAdd(&y[t + 3], acc3);
}

// ---------------- host ----------------

extern "C" void kernel_launch(void* const* d_in, const int* in_sizes, int n_in,
                              void* d_out, int out_size, void* d_ws, size_t ws_size,
                              hipStream_t stream) {
  const float* u  = (const float*)d_in[0];
  const float* A  = (const float*)d_in[1];
  const float* B  = (const float*)d_in[2];
  const float* Cm = (const float*)d_in[3];
  const float* ls = (const float*)d_in[4];
  float* y  = (float*)d_out;
  float* ws = (float*)d_ws;

  const int N = N_DIM;
  const size_t NN = (size_t)N * N;
  float* b0 = ws;
  float* b1 = b0 + NN;
  float* b2 = b1 + NN;
  float* V  = b2 + NN;               // N x 128
  float* W  = V + (size_t)N * 128;   // 128 x N
  float* Kv = W + (size_t)128 * N;   // L
  float* P  = Kv + L_SEQ;            // NPART x NN partials
  ushort_t* setA = (ushort_t*)(P + (size_t)NPART * NN);  // {H,M,HT,MT}
  ushort_t* setB = setA + 4 * NN;

  hipMemsetAsync(V,  0, (size_t)N * 128 * sizeof(float), stream);
  hipMemsetAsync(W,  0, (size_t)128 * N * sizeof(float), stream);
  hipMemsetAsync(Kv, 0, (size_t)L_SEQ * sizeof(float), stream);
  hipMemsetAsync(y,  0, (size_t)L_SEQ * sizeof(float), stream);
  hipMemcpyAsync(W, Cm, N * sizeof(float), hipMemcpyDeviceToDevice, stream);

  dim3 g16(16, 16);
  dim3 gK(16, 16, NPART);
  auto gemm = [&](float* C, int ldc, const float* Am, int lda,
                  const float* Bmm, int ldb, const float* D, int ldd,
                  int M, int Nn, int K, int ks, int flags) {
    dim3 g((M + 63) / 64, (Nn + 63) / 64, ks);
    gemm_k<<<g, 256, 0, stream>>>(Am, lda, Bmm, ldb, C, ldc, D, ldd,
                                  M, Nn, K, K / ks, flags);
  };
  auto square = [&](const ushort_t* in, float* fout, ushort_t* sout, int flags) {
    gemm4<<<gK, 256, 0, stream>>>(in, in + 2 * NN, P, N / NPART);
    k_splitred<<<g16, 256, 0, stream>>>(P, NPART, nullptr, fout, sout, flags);
  };

  // E = (step/2)*A ; splits of E -> setA
  k_scaleE<<<NN / 256, 256, 0, stream>>>(b0, A, ls);
  k_splitred<<<g16, 256, 0, stream>>>(b0, 1, nullptr, nullptr, setA,
                                      FW_SPLIT | FW_TSPLIT);
  // E2 = E*E  (fp32 -> b1, T-splits -> setB)
  gemm4<<<gK, 256, 0, stream>>>(setA, setA + 2 * NN, P, N / NPART);
  k_splitred<<<g16, 256, 0, stream>>>(P, NPART, nullptr, b1, setB,
                                      FW_F32 | FW_TSPLIT);
  // S1 = E + E2 ; row-splits of S1 -> setA
  k_add<<<NN / 256, 256, 0, stream>>>(b2, b0, b1);
  k_splitred<<<g16, 256, 0, stream>>>(b2, 1, nullptr, nullptr, setA, FW_SPLIT);
  // S = S1*E2 + S1  (fp32 -> b0)
  gemm4<<<gK, 256, 0, stream>>>(setA, setB + 2 * NN, P, N / NPART);
  k_splitred<<<g16, 256, 0, stream>>>(P, NPART, b2, b0, setA, FW_F32 | FW_ADDD);
  // Bb -> V[:,0] ; Ab = I + 2S -> b1 ; splits of Ab -> setA
  k_bb<<<256, 256, 0, stream>>>(V, b0, B, ls);
  k_mkAb<<<NN / 256, 256, 0, stream>>>(b1, b0);
  k_splitred<<<g16, 256, 0, stream>>>(b1, 1, nullptr, nullptr, setA,
                                      FW_SPLIT | FW_TSPLIT);

  float* curf = b1;
  float* freef[2] = {b2, b0};
  int ff = 0;
  ushort_t* curs = setA;
  ushort_t* oths = setB;

  // Right Krylov doubling: V[:, s:2s] = Ab^s * V[:, :s]; square the power.
  for (int j = 0; j < 7; ++j) {
    int s = 1 << j;
    gemm(V + s, 128, curf, N, V, 128, nullptr, 0, N, s, N, 8, 1);
    float* nf = freef[ff];
    square(curs, nf, oths, FW_F32 | FW_SPLIT | FW_TSPLIT);
    freef[ff] = curf; curf = nf; ff ^= 1;
    ushort_t* tmp = curs; curs = oths; oths = tmp;
  }
  // Left Krylov doubling: W[r:2r,:] = W[:r,:] * Q; square Q.
  for (int j = 0; j < 7; ++j) {
    int rr = 1 << j;
    gemm(W + (size_t)rr * N, N, W, N, curf, N, nullptr, 0, rr, N, N, 8, 1);
    if (j < 6) {
      float* nf = freef[ff];
      int fl = (j == 5) ? FW_F32 : (FW_F32 | FW_SPLIT | FW_TSPLIT);
      square(curs, nf, oths, fl);
      freef[ff] = curf; curf = nf; ff ^= 1;
      ushort_t* tmp = curs; curs = oths; oths = tmp;
    }
  }
  // K[128q + r] = W[q,:] . V[:,r]
  gemm(Kv, 128, W, N, V, 128, nullptr, 0, 128, 128, N, 8, 1);
  // y = causal conv(K, u)
  conv_k<<<dim3(16, 16), 256, 0, stream>>>(Kv, u, y);
}